// Round 8
// baseline (336.504 us; speedup 1.0000x reference)
//
#include <hip/hip_runtime.h>
#include <hip/hip_bf16.h>

typedef _Float16 f16;
typedef _Float16 f16x4 __attribute__((ext_vector_type(4)));
typedef _Float16 f16x8 __attribute__((ext_vector_type(8)));
typedef float f32x4 __attribute__((ext_vector_type(4)));

#define N_TOK  8192
#define DMODEL 2048
#define HDIM   1024
#define NEXP   8
#define MAX_ROWS 17408   // 16384 pairs + 8 experts * 127 padding, rounded to 128
#define ROW_TILES 136    // MAX_ROWS / 128

__device__ inline void gload16(const void* g, void* l) {
    __builtin_amdgcn_global_load_lds((const __attribute__((address_space(1))) void*)g,
                                     (__attribute__((address_space(3))) void*)l, 16, 0, 0);
}

// ---------------- gating body (wave per token) -----------------------------
__device__ inline void gating_body(
    int blk, int tid,
    const float* __restrict__ x, const float* __restrict__ Wg,
    f16* __restrict__ x16, int* __restrict__ ch_e, float* __restrict__ ch_w,
    float* __restrict__ gates_out)
{
    const int wv = tid >> 6, ln = tid & 63;
    const int token = blk * 4 + wv;
    const long rowb = (long)token * DMODEL;

    double acc[NEXP] = {};
    #pragma unroll
    for (int t = 0; t < 8; ++t) {
        const int v4 = t * 64 + ln;                    // float4 index in row
        float4 a = *(const float4*)(x + rowb + (size_t)v4 * 4);
        f16x4 h; h[0] = (f16)a.x; h[1] = (f16)a.y; h[2] = (f16)a.z; h[3] = (f16)a.w;
        *(f16x4*)(x16 + rowb + (size_t)v4 * 4) = h;
        float xs[4] = {a.x, a.y, a.z, a.w};
        #pragma unroll
        for (int j = 0; j < 4; ++j) {
            const float4* wr_ = (const float4*)(Wg + (size_t)(v4 * 4 + j) * 8);
            float4 w0 = wr_[0], w1 = wr_[1];
            double xv = (double)xs[j];
            acc[0] += xv * w0.x; acc[1] += xv * w0.y;
            acc[2] += xv * w0.z; acc[3] += xv * w0.w;
            acc[4] += xv * w1.x; acc[5] += xv * w1.y;
            acc[6] += xv * w1.z; acc[7] += xv * w1.w;
        }
    }
    #pragma unroll
    for (int e = 0; e < NEXP; ++e) {
        double v = acc[e];
        #pragma unroll
        for (int s = 32; s; s >>= 1) v += __shfl_xor(v, s);
        acc[e] = v;
    }
    if (ln == 0) {
        // top-2 on logits (softmax strictly monotone; ties -> lowest index)
        int e0 = 0;
        #pragma unroll
        for (int e = 1; e < NEXP; ++e) if (acc[e] > acc[e0]) e0 = e;
        int e1 = (e0 == 0) ? 1 : 0;
        #pragma unroll
        for (int e = 0; e < NEXP; ++e) if (e != e0 && acc[e] > acc[e1]) e1 = e;
        float mx = (float)acc[e0];
        float g[NEXP], s = 0.f;
        #pragma unroll
        for (int e = 0; e < NEXP; ++e) { g[e] = __expf((float)acc[e] - mx); s += g[e]; }
        float inv = 1.f / s;
        #pragma unroll
        for (int e = 0; e < NEXP; ++e) g[e] *= inv;
        ch_e[token * 2] = e0; ch_e[token * 2 + 1] = e1;
        ch_w[token * 2] = g[e0]; ch_w[token * 2 + 1] = g[e1];
        float4 g0 = {g[0], g[1], g[2], g[3]}, g1 = {g[4], g[5], g[6], g[7]};
        *(float4*)(gates_out + (size_t)token * 8) = g0;
        *(float4*)(gates_out + (size_t)token * 8 + 4) = g1;
    }
}

// ---------------- transpose body: W[e] [R][C] fp32 -> Wt[e] [C][R] fp16 ----
// Vectorized: float4 loads (16B/lane), f16x8 stores (16B/lane).
__device__ inline void transpose_body(
    int e, int c0, int r0, int tid,
    const float* __restrict__ W, f16* __restrict__ Wt, int R, int C)
{
    __shared__ float t[64][65];
    const float* Wm = W + (size_t)e * R * C;
    f16* Wo = Wt + (size_t)e * R * C;

    // read: thread (tid>>4, tid&15): rows (tid>>4)+16i, float4 at col (tid&15)*4
    const int rr4 = tid >> 4, c4 = (tid & 15) * 4;
    #pragma unroll
    for (int i = 0; i < 4; ++i) {
        int r = rr4 + i * 16;
        float4 v = *(const float4*)(Wm + (size_t)(r0 + r) * C + c0 + c4);
        t[r][c4] = v.x; t[r][c4 + 1] = v.y; t[r][c4 + 2] = v.z; t[r][c4 + 3] = v.w;
    }
    __syncthreads();

    // write: thread (tid>>3, tid&7): col cc = (tid>>3)+32i, f16x8 at row (tid&7)*8
    const int cc8 = tid >> 3, r8 = (tid & 7) * 8;
    #pragma unroll
    for (int i = 0; i < 2; ++i) {
        int cc = cc8 + i * 32;
        f16x8 h;
        #pragma unroll
        for (int q = 0; q < 8; ++q) h[q] = (f16)t[r8 + q][cc];
        *(f16x8*)(Wo + (size_t)(c0 + cc) * R + r0 + r8) = h;
    }
}

// ---------------- fused prep: gating + W1 transpose + W2 transpose ---------
// blocks [0,2048): gating; [2048,6144): W1t; [6144,10240): W2t
__global__ __launch_bounds__(256) void prep_k(
    const float* __restrict__ x, const float* __restrict__ Wg,
    const float* __restrict__ W1, const float* __restrict__ W2,
    f16* __restrict__ x16, f16* __restrict__ W1t, f16* __restrict__ W2t,
    int* __restrict__ ch_e, float* __restrict__ ch_w, float* __restrict__ gates_out)
{
    const int b = blockIdx.x, tid = threadIdx.x;
    if (b < 2048) {
        gating_body(b, tid, x, Wg, x16, ch_e, ch_w, gates_out);
    } else if (b < 6144) {
        const int idx = b - 2048;                 // e * (16*32) sections
        const int e = idx >> 9, rem = idx & 511;
        const int c0 = (rem & 15) * 64, r0 = (rem >> 4) * 64;
        transpose_body(e, c0, r0, tid, W1, W1t, DMODEL, HDIM);
    } else {
        const int idx = b - 6144;
        const int e = idx >> 9, rem = idx & 511;
        const int c0 = (rem & 31) * 64, r0 = (rem >> 5) * 64;
        transpose_body(e, c0, r0, tid, W2, W2t, HDIM, DMODEL);
    }
}

// ---------------- route: counts + loss + offsets + deterministic lists -----
// Single block, 1024 threads. Thread t owns tokens [8t, 8t+8).
#define TPB_R 1024
#define TOK_T 8
__global__ __launch_bounds__(TPB_R) void route_k(
    const int* __restrict__ ch_e, const float* __restrict__ gates,
    int* __restrict__ poff, int* __restrict__ tok_list, int* __restrict__ pair_list,
    float* __restrict__ loss_out)
{
    __shared__ int scnt[TPB_R][NEXP];     // per-thread expert counts -> exclusive prefixes
    __shared__ int lpoff[NEXP + 1];
    __shared__ int ltot[NEXP];
    __shared__ float redl[16][NEXP];

    const int t = threadIdx.x;
    const int wv = t >> 6, ln = t & 63;

    int es[TOK_T * 2];
    #pragma unroll
    for (int i = 0; i < TOK_T; ++i) {
        int2 ee = *(const int2*)(ch_e + (size_t)(t * TOK_T + i) * 2);
        es[2 * i] = ee.x; es[2 * i + 1] = ee.y;
    }
    float lsum[NEXP] = {};
    #pragma unroll
    for (int i = 0; i < TOK_T; ++i) {
        const float4* gp = (const float4*)(gates + (size_t)(t * TOK_T + i) * 8);
        float4 a = gp[0], b = gp[1];
        lsum[0] += a.x; lsum[1] += a.y; lsum[2] += a.z; lsum[3] += a.w;
        lsum[4] += b.x; lsum[5] += b.y; lsum[6] += b.z; lsum[7] += b.w;
    }
    #pragma unroll
    for (int e = 0; e < NEXP; ++e) {
        int c = 0;
        #pragma unroll
        for (int i = 0; i < TOK_T * 2; ++i) c += (es[i] == e);
        scnt[t][e] = c;
        float v = lsum[e];
        #pragma unroll
        for (int s = 32; s; s >>= 1) v += __shfl_xor(v, s);
        lsum[e] = v;
    }
    if (ln == 0) {
        #pragma unroll
        for (int e = 0; e < NEXP; ++e) redl[wv][e] = lsum[e];
    }
    __syncthreads();

    // exclusive prefix over the 1024 per-thread counts; wave e scans expert e
    if (wv < NEXP) {
        const int e = wv;
        int run = 0;
        #pragma unroll
        for (int i = 0; i < 16; ++i) {
            int idx = ln * 16 + i;
            int tmp = scnt[idx][e];
            scnt[idx][e] = run;
            run += tmp;
        }
        int incl = run;
        #pragma unroll
        for (int s = 1; s < 64; s <<= 1) {
            int v = __shfl_up(incl, s);
            if (ln >= s) incl += v;
        }
        int excl = incl - run;
        #pragma unroll
        for (int i = 0; i < 16; ++i) scnt[ln * 16 + i][e] += excl;
        if (ln == 63) ltot[e] = incl;
    }
    __syncthreads();
    if (t == 0) {
        int off = 0;
        #pragma unroll
        for (int e = 0; e < NEXP; ++e) { lpoff[e] = off; poff[e] = off; off += ((ltot[e] + 127) & ~127); }
        lpoff[NEXP] = off; poff[NEXP] = off;
        // loss
        float ep[NEXP];
        #pragma unroll
        for (int e = 0; e < NEXP; ++e) {
            float s = 0.f;
            for (int w = 0; w < 16; ++w) s += redl[w][e];
            ep[e] = s * (1.f / (float)N_TOK);
        }
        float m = 0.f;
        #pragma unroll
        for (int e = 0; e < NEXP; ++e) m += ep[e];
        m *= (1.f / NEXP);
        float var = 0.f;
        #pragma unroll
        for (int e = 0; e < NEXP; ++e) { float d = ep[e] - m; var += d * d; }
        var *= (1.f / NEXP);
        loss_out[0] = var / (m * m + 1e-10f);
    }
    __syncthreads();

    // emit lists: row = poff[e] + prefix[t][e] + rank-within-thread (token order)
    #pragma unroll
    for (int i = 0; i < TOK_T * 2; ++i) {
        int e = es[i];
        int rank = 0;
        #pragma unroll
        for (int j = 0; j < i; ++j) rank += (es[j] == e);
        int row = lpoff[e] + scnt[t][e] + rank;
        int n = t * TOK_T + (i >> 1);
        tok_list[row] = n;
        pair_list[row] = n * 2 + (i & 1);
    }
}

// ---------------- grouped GEMM (m97 structure, fp16, 2-D XCD rectangles) ---
// G1: h = silu(x16[gather] @ W1t^T)   [rows x 1024], K=2048 -> hbuf fp16
// G2: Yp[pair] = h @ W2t^T            [rows x 2048], K=1024 -> fp16, no atomics
// Each XCD owns 17 rts x all cts; rt-groups {4,4,4,5} sweep cts, rt fastest.
template<bool G1>
__global__ __launch_bounds__(256, 3) void ggemm_k(
    const f16* __restrict__ A, const f16* __restrict__ Wt,
    const int* __restrict__ poff,
    const int* __restrict__ tok_list, const int* __restrict__ pair_list,
    f16* __restrict__ Hout, f16* __restrict__ Yp)
{
    constexpr int K   = G1 ? DMODEL : HDIM;
    constexpr int NJ  = G1 ? HDIM : DMODEL;
    constexpr int NCT = NJ / 128;

    __shared__ int s_off[NEXP + 1];
    __shared__ f16 lA[128 * 64];
    __shared__ f16 lB[128 * 64];

    if (threadIdx.x < NEXP + 1) s_off[threadIdx.x] = poff[threadIdx.x];
    __syncthreads();

    // block -> (rt, ct): xcd rectangle decomposition (136 = 8 xcd * 17 rt)
    const int xcd = blockIdx.x & 7;
    const int i   = blockIdx.x >> 3;            // [0, 17*NCT)
    int rloc, ct;
    if (i < 12 * NCT) {
        const int g = i / (4 * NCT), r = i % (4 * NCT);
        rloc = g * 4 + (r & 3);
        ct   = r >> 2;
    } else {
        const int j = i - 12 * NCT;
        rloc = 12 + j % 5;
        ct   = j / 5;
    }
    const int rt = xcd * 17 + rloc;

    const int row0 = rt * 128;
    if (row0 >= s_off[NEXP]) return;
    int e = 0;
    #pragma unroll
    for (int ii = 0; ii < NEXP - 1; ++ii) if (row0 >= s_off[ii + 1]) e = ii + 1;

    const int wv = threadIdx.x >> 6, ln = threadIdx.x & 63;

    // staging sources (pre-swizzled chunk; c is ii-independent: (8*ii)&7==0)
    const int rbase = 32 * wv + (ln >> 3);        // tile row for ii=0
    const int c     = (ln & 7) ^ (ln >> 3);       // swizzled 16B chunk
    const f16* srcA[4];
    if (G1) {
        #pragma unroll
        for (int ii = 0; ii < 4; ++ii)
            srcA[ii] = A + (long)tok_list[row0 + rbase + 8 * ii] * DMODEL + c * 8;
    } else {
        srcA[0] = A + (long)(row0 + rbase) * HDIM + c * 8;
    }
    const f16* srcB = Wt + ((long)e * NJ + ct * 128 + rbase) * K + c * 8;

    f32x4 acc[4][4] = {};
    const int wr = wv >> 1, wc = wv & 1;
    const int l16 = ln & 15, lk = ln >> 4;

    for (int k0 = 0; k0 < K; k0 += 64) {
        #pragma unroll
        for (int ii = 0; ii < 4; ++ii) {
            const f16* sa = G1 ? (srcA[ii] + k0) : (srcA[0] + (size_t)(8 * ii) * K + k0);
            gload16(sa, &lA[(32 * wv + 8 * ii) * 64]);
            gload16(srcB + (size_t)(8 * ii) * K + k0, &lB[(32 * wv + 8 * ii) * 64]);
        }
        __syncthreads();
        #pragma unroll
        for (int kk = 0; kk < 2; ++kk) {
            f16x8 af[4], bf[4];
            #pragma unroll
            for (int m = 0; m < 4; ++m) {
                int r = wr * 64 + m * 16 + l16;
                int ch = (kk * 4 + lk) ^ (r & 7);
                af[m] = *(const f16x8*)&lA[r * 64 + ch * 8];
            }
            #pragma unroll
            for (int n = 0; n < 4; ++n) {
                int j = wc * 64 + n * 16 + l16;
                int ch = (kk * 4 + lk) ^ (j & 7);
                bf[n] = *(const f16x8*)&lB[j * 64 + ch * 8];
            }
            #pragma unroll
            for (int m = 0; m < 4; ++m)
                #pragma unroll
                for (int n = 0; n < 4; ++n)
                    acc[m][n] = __builtin_amdgcn_mfma_f32_16x16x32_f16(af[m], bf[n], acc[m][n], 0, 0, 0);
        }
        __syncthreads();
    }

    if (G1) {
        #pragma unroll
        for (int m = 0; m < 4; ++m) {
            int rb = row0 + wr * 64 + m * 16 + lk * 4;
            #pragma unroll
            for (int n = 0; n < 4; ++n) {
                int cc = ct * 128 + wc * 64 + n * 16 + l16;
                #pragma unroll
                for (int j2 = 0; j2 < 4; ++j2) {
                    float v = acc[m][n][j2];
                    v = v / (1.f + __expf(-v));           // silu
                    Hout[(long)(rb + j2) * HDIM + cc] = (f16)v;
                }
            }
        }
    } else {
        #pragma unroll
        for (int m = 0; m < 4; ++m) {
            int rb = row0 + wr * 64 + m * 16 + lk * 4;
            #pragma unroll
            for (int j2 = 0; j2 < 4; ++j2) {
                int p = pair_list[rb + j2];
                if (p >= 0) {
                    f16* yp = Yp + (long)p * DMODEL + ct * 128 + wc * 64 + l16;
                    #pragma unroll
                    for (int n = 0; n < 4; ++n)
                        yp[n * 16] = (f16)acc[m][n][j2];
                }
            }
        }
    }
}

// ---------------- combine: out[n] = w0*Yp[2n] + w1*Yp[2n+1] ----------------
__global__ __launch_bounds__(256) void combine_k(
    const f16* __restrict__ Yp, const float* __restrict__ ch_w,
    float* __restrict__ out)
{
    const int n = blockIdx.x, t = threadIdx.x;
    const float w0 = ch_w[n * 2], w1 = ch_w[n * 2 + 1];
    const f16x8 a = *(const f16x8*)(Yp + ((long)n * 2) * DMODEL + t * 8);
    const f16x8 b = *(const f16x8*)(Yp + ((long)n * 2 + 1) * DMODEL + t * 8);
    float4 o0, o1;
    o0.x = w0 * (float)a[0] + w1 * (float)b[0];
    o0.y = w0 * (float)a[1] + w1 * (float)b[1];
    o0.z = w0 * (float)a[2] + w1 * (float)b[2];
    o0.w = w0 * (float)a[3] + w1 * (float)b[3];
    o1.x = w0 * (float)a[4] + w1 * (float)b[4];
    o1.y = w0 * (float)a[5] + w1 * (float)b[5];
    o1.z = w0 * (float)a[6] + w1 * (float)b[6];
    o1.w = w0 * (float)a[7] + w1 * (float)b[7];
    float* op = out + (long)n * DMODEL + t * 8;
    *(float4*)op = o0;
    *(float4*)(op + 4) = o1;
}

// ---------------- launch ---------------------------------------------------
extern "C" void kernel_launch(void* const* d_in, const int* in_sizes, int n_in,
                              void* d_out, int out_size, void* d_ws, size_t ws_size,
                              hipStream_t stream)
{
    const float* x  = (const float*)d_in[0];
    const float* Wg = (const float*)d_in[1];
    const float* W1 = (const float*)d_in[2];
    const float* W2 = (const float*)d_in[3];
    float* out = (float*)d_out;

    char* ws = (char*)d_ws;
    size_t o = 0;
    auto alloc = [&](size_t bytes) { size_t r = o; o = (o + bytes + 255) & ~(size_t)255; return r; };
    int*   poff      = (int*)(ws + alloc((NEXP + 1) * 4));
    float* gates     = (float*)(ws + alloc((size_t)N_TOK * NEXP * 4));
    int*   ch_e      = (int*)(ws + alloc((size_t)N_TOK * 2 * 4));
    float* ch_w      = (float*)(ws + alloc((size_t)N_TOK * 2 * 4));
    int*   tok_list  = (int*)(ws + alloc((size_t)MAX_ROWS * 4));
    int*   pair_list = (int*)(ws + alloc((size_t)MAX_ROWS * 4));
    f16*   x16       = (f16*)(ws + alloc((size_t)N_TOK * DMODEL * 2));          // 32 MiB
    f16*   W1t       = (f16*)(ws + alloc((size_t)NEXP * DMODEL * HDIM * 2));    // 32 MiB, contiguous after x16
    f16*   W2t       = (f16*)(ws + alloc((size_t)NEXP * DMODEL * HDIM * 2));
    f16*   hbuf      = (f16*)(ws + alloc((size_t)MAX_ROWS * HDIM * 2));
    // Yp (N_TOK*2 x DMODEL fp16 = 64 MiB) aliases [x16][W1t] — both dead before G2 writes it.
    f16*   Yp        = x16;
    (void)ws_size; (void)in_sizes; (void)n_in;

    hipMemsetAsync(tok_list, 0, (size_t)MAX_ROWS * 4, stream);
    hipMemsetAsync(pair_list, 0xFF, (size_t)MAX_ROWS * 4, stream);   // -1 = padding row

    prep_k<<<10240, 256, 0, stream>>>(x, Wg, W1, W2, x16, W1t, W2t, ch_e, ch_w, gates);
    route_k<<<1, TPB_R, 0, stream>>>(ch_e, gates, poff, tok_list, pair_list,
                                     out + (size_t)N_TOK * DMODEL);
    ggemm_k<true ><<<ROW_TILES * (HDIM / 128), 256, 0, stream>>>(x16, W1t, poff, tok_list, pair_list, hbuf, nullptr);
    ggemm_k<false><<<ROW_TILES * (DMODEL / 128), 256, 0, stream>>>(hbuf, W2t, poff, tok_list, pair_list, nullptr, Yp);
    combine_k<<<N_TOK, 256, 0, stream>>>(Yp, ch_w, out);
}

// Round 9
// 306.955 us; speedup vs baseline: 1.0963x; 1.0963x over previous
//
#include <hip/hip_runtime.h>
#include <hip/hip_bf16.h>

typedef _Float16 f16;
typedef _Float16 f16x4 __attribute__((ext_vector_type(4)));
typedef _Float16 f16x8 __attribute__((ext_vector_type(8)));
typedef float f32x4 __attribute__((ext_vector_type(4)));

#define N_TOK  8192
#define DMODEL 2048
#define HDIM   1024
#define NEXP   8
#define MAX_ROWS 17408   // 16384 pairs + 8 experts * 127 padding, rounded to 128
#define ROW_TILES 136    // MAX_ROWS / 128

__device__ inline void gload16(const void* g, void* l) {
    __builtin_amdgcn_global_load_lds((const __attribute__((address_space(1))) void*)g,
                                     (__attribute__((address_space(3))) void*)l, 16, 0, 0);
}

// ---------------- fused prep: gating + W1 transpose + W2 transpose ---------
// 1024 threads/block. LDS = union{ Wg staged [e][k] 64KB | 4 transpose tiles }.
// 66.5KB -> 2 blocks/CU = 2048 thr/CU (full occupancy).
// blocks [0,512): gating (16 tokens each); [512,1536): W1t; [1536,2560): W2t
union PrepSm {
    float wg[NEXP][DMODEL];     // transposed gate weights
    float t[4][64][65];         // 4 transpose tiles
};

__device__ inline void transpose_body(
    int e, int c0, int r0, int tid, float (*t)[65],
    const float* __restrict__ W, f16* __restrict__ Wt, int R, int C)
{
    const float* Wm = W + (size_t)e * R * C;
    f16* Wo = Wt + (size_t)e * R * C;

    // read: thread (tid>>4, tid&15): rows (tid>>4)+16i, float4 at col (tid&15)*4
    const int rr4 = tid >> 4, c4 = (tid & 15) * 4;
    #pragma unroll
    for (int i = 0; i < 4; ++i) {
        int r = rr4 + i * 16;
        float4 v = *(const float4*)(Wm + (size_t)(r0 + r) * C + c0 + c4);
        t[r][c4] = v.x; t[r][c4 + 1] = v.y; t[r][c4 + 2] = v.z; t[r][c4 + 3] = v.w;
    }
    __syncthreads();

    // write: thread (tid>>3, tid&7): col cc = (tid>>3)+32i, f16x8 at row (tid&7)*8
    const int cc8 = tid >> 3, r8 = (tid & 7) * 8;
    #pragma unroll
    for (int i = 0; i < 2; ++i) {
        int cc = cc8 + i * 32;
        f16x8 h;
        #pragma unroll
        for (int q = 0; q < 8; ++q) h[q] = (f16)t[r8 + q][cc];
        *(f16x8*)(Wo + (size_t)(c0 + cc) * R + r0 + r8) = h;
    }
}

__global__ __launch_bounds__(1024) void prep_k(
    const float* __restrict__ x, const float* __restrict__ Wg,
    const float* __restrict__ W1, const float* __restrict__ W2,
    f16* __restrict__ x16, f16* __restrict__ W1t, f16* __restrict__ W2t,
    int* __restrict__ ch_e, float* __restrict__ ch_w, float* __restrict__ gates_out)
{
    __shared__ PrepSm sm;
    const int b = blockIdx.x, tid = threadIdx.x;

    if (b < 512) {
        // ---- stage Wg [k][e] -> LDS [e][k], fully coalesced global reads ----
        #pragma unroll
        for (int it = 0; it < 4; ++it) {
            int f = it * 1024 + tid;              // float4 index into Wg
            int k = f >> 1, e0 = (f & 1) * 4;
            float4 v = *(const float4*)(Wg + (size_t)f * 4);
            sm.wg[e0][k] = v.x; sm.wg[e0 + 1][k] = v.y;
            sm.wg[e0 + 2][k] = v.z; sm.wg[e0 + 3][k] = v.w;
        }
        __syncthreads();

        // ---- gating: wave per token, Wg from LDS (conflict-free b128) ----
        const int wv = tid >> 6, ln = tid & 63;
        const int token = b * 16 + wv;
        const long rowb = (long)token * DMODEL;

        double acc[NEXP] = {};
        #pragma unroll
        for (int t = 0; t < 8; ++t) {
            const int v4 = t * 64 + ln;                    // float4 index in row
            float4 a = *(const float4*)(x + rowb + (size_t)v4 * 4);
            f16x4 h; h[0] = (f16)a.x; h[1] = (f16)a.y; h[2] = (f16)a.z; h[3] = (f16)a.w;
            *(f16x4*)(x16 + rowb + (size_t)v4 * 4) = h;
            float xs[4] = {a.x, a.y, a.z, a.w};
            #pragma unroll
            for (int e = 0; e < NEXP; ++e) {
                float4 w = *(const float4*)&sm.wg[e][v4 * 4];
                acc[e] += (double)xs[0] * w.x + (double)xs[1] * w.y
                        + (double)xs[2] * w.z + (double)xs[3] * w.w;
            }
        }
        #pragma unroll
        for (int e = 0; e < NEXP; ++e) {
            double v = acc[e];
            #pragma unroll
            for (int s = 32; s; s >>= 1) v += __shfl_xor(v, s);
            acc[e] = v;
        }
        if (ln == 0) {
            // top-2 on logits (softmax strictly monotone; ties -> lowest index)
            int e0 = 0;
            #pragma unroll
            for (int e = 1; e < NEXP; ++e) if (acc[e] > acc[e0]) e0 = e;
            int e1 = (e0 == 0) ? 1 : 0;
            #pragma unroll
            for (int e = 0; e < NEXP; ++e) if (e != e0 && acc[e] > acc[e1]) e1 = e;
            float mx = (float)acc[e0];
            float g[NEXP], s = 0.f;
            #pragma unroll
            for (int e = 0; e < NEXP; ++e) { g[e] = __expf((float)acc[e] - mx); s += g[e]; }
            float inv = 1.f / s;
            #pragma unroll
            for (int e = 0; e < NEXP; ++e) g[e] *= inv;
            ch_e[token * 2] = e0; ch_e[token * 2 + 1] = e1;
            ch_w[token * 2] = g[e0]; ch_w[token * 2 + 1] = g[e1];
            float4 g0 = {g[0], g[1], g[2], g[3]}, g1 = {g[4], g[5], g[6], g[7]};
            *(float4*)(gates_out + (size_t)token * 8) = g0;
            *(float4*)(gates_out + (size_t)token * 8 + 4) = g1;
        }
    } else if (b < 1536) {
        const int g = (b - 512) * 4 + (tid >> 8);  // global tile id
        const int e = g >> 9, rem = g & 511;
        const int c0 = (rem & 15) * 64, r0 = (rem >> 4) * 64;
        transpose_body(e, c0, r0, tid & 255, sm.t[tid >> 8], W1, W1t, DMODEL, HDIM);
    } else {
        const int g = (b - 1536) * 4 + (tid >> 8);
        const int e = g >> 9, rem = g & 511;
        const int c0 = (rem & 31) * 64, r0 = (rem >> 5) * 64;
        transpose_body(e, c0, r0, tid & 255, sm.t[tid >> 8], W2, W2t, HDIM, DMODEL);
    }
}

// ---------------- route: counts + loss + offsets + deterministic lists -----
// Single block, 1024 threads. Thread t owns tokens [8t, 8t+8).
#define TPB_R 1024
#define TOK_T 8
__global__ __launch_bounds__(TPB_R) void route_k(
    const int* __restrict__ ch_e, const float* __restrict__ gates,
    int* __restrict__ poff, int* __restrict__ tok_list, int* __restrict__ pair_list,
    float* __restrict__ loss_out)
{
    __shared__ int scnt[TPB_R][NEXP];     // per-thread expert counts -> exclusive prefixes
    __shared__ int lpoff[NEXP + 1];
    __shared__ int ltot[NEXP];
    __shared__ float redl[16][NEXP];

    const int t = threadIdx.x;
    const int wv = t >> 6, ln = t & 63;

    int es[TOK_T * 2];
    #pragma unroll
    for (int i = 0; i < TOK_T; ++i) {
        int2 ee = *(const int2*)(ch_e + (size_t)(t * TOK_T + i) * 2);
        es[2 * i] = ee.x; es[2 * i + 1] = ee.y;
    }
    float lsum[NEXP] = {};
    #pragma unroll
    for (int i = 0; i < TOK_T; ++i) {
        const float4* gp = (const float4*)(gates + (size_t)(t * TOK_T + i) * 8);
        float4 a = gp[0], b = gp[1];
        lsum[0] += a.x; lsum[1] += a.y; lsum[2] += a.z; lsum[3] += a.w;
        lsum[4] += b.x; lsum[5] += b.y; lsum[6] += b.z; lsum[7] += b.w;
    }
    #pragma unroll
    for (int e = 0; e < NEXP; ++e) {
        int c = 0;
        #pragma unroll
        for (int i = 0; i < TOK_T * 2; ++i) c += (es[i] == e);
        scnt[t][e] = c;
        float v = lsum[e];
        #pragma unroll
        for (int s = 32; s; s >>= 1) v += __shfl_xor(v, s);
        lsum[e] = v;
    }
    if (ln == 0) {
        #pragma unroll
        for (int e = 0; e < NEXP; ++e) redl[wv][e] = lsum[e];
    }
    __syncthreads();

    // exclusive prefix over the 1024 per-thread counts; wave e scans expert e
    if (wv < NEXP) {
        const int e = wv;
        int run = 0;
        #pragma unroll
        for (int i = 0; i < 16; ++i) {
            int idx = ln * 16 + i;
            int tmp = scnt[idx][e];
            scnt[idx][e] = run;
            run += tmp;
        }
        int incl = run;
        #pragma unroll
        for (int s = 1; s < 64; s <<= 1) {
            int v = __shfl_up(incl, s);
            if (ln >= s) incl += v;
        }
        int excl = incl - run;
        #pragma unroll
        for (int i = 0; i < 16; ++i) scnt[ln * 16 + i][e] += excl;
        if (ln == 63) ltot[e] = incl;
    }
    __syncthreads();
    if (t == 0) {
        int off = 0;
        #pragma unroll
        for (int e = 0; e < NEXP; ++e) { lpoff[e] = off; poff[e] = off; off += ((ltot[e] + 127) & ~127); }
        lpoff[NEXP] = off; poff[NEXP] = off;
        // loss
        float ep[NEXP];
        #pragma unroll
        for (int e = 0; e < NEXP; ++e) {
            float s = 0.f;
            for (int w = 0; w < 16; ++w) s += redl[w][e];
            ep[e] = s * (1.f / (float)N_TOK);
        }
        float m = 0.f;
        #pragma unroll
        for (int e = 0; e < NEXP; ++e) m += ep[e];
        m *= (1.f / NEXP);
        float var = 0.f;
        #pragma unroll
        for (int e = 0; e < NEXP; ++e) { float d = ep[e] - m; var += d * d; }
        var *= (1.f / NEXP);
        loss_out[0] = var / (m * m + 1e-10f);
    }
    __syncthreads();

    // emit lists: row = poff[e] + prefix[t][e] + rank-within-thread (token order)
    #pragma unroll
    for (int i = 0; i < TOK_T * 2; ++i) {
        int e = es[i];
        int rank = 0;
        #pragma unroll
        for (int j = 0; j < i; ++j) rank += (es[j] == e);
        int row = lpoff[e] + scnt[t][e] + rank;
        int n = t * TOK_T + (i >> 1);
        tok_list[row] = n;
        pair_list[row] = n * 2 + (i & 1);
    }
}

// ---------------- grouped GEMM (m97 structure, fp16, 2-D XCD rectangles) ---
// G1: h = silu(x16[gather] @ W1t^T)   [rows x 1024], K=2048 -> hbuf fp16
// G2: Yp[pair] = h @ W2t^T            [rows x 2048], K=1024 -> fp16, no atomics
// Each XCD owns 17 rts x all cts; rt-groups {4,4,4,5} sweep cts, rt fastest.
template<bool G1>
__global__ __launch_bounds__(256, 3) void ggemm_k(
    const f16* __restrict__ A, const f16* __restrict__ Wt,
    const int* __restrict__ poff,
    const int* __restrict__ tok_list, const int* __restrict__ pair_list,
    f16* __restrict__ Hout, f16* __restrict__ Yp)
{
    constexpr int K   = G1 ? DMODEL : HDIM;
    constexpr int NJ  = G1 ? HDIM : DMODEL;
    constexpr int NCT = NJ / 128;

    __shared__ int s_off[NEXP + 1];
    __shared__ f16 lA[128 * 64];
    __shared__ f16 lB[128 * 64];

    if (threadIdx.x < NEXP + 1) s_off[threadIdx.x] = poff[threadIdx.x];
    __syncthreads();

    // block -> (rt, ct): xcd rectangle decomposition (136 = 8 xcd * 17 rt)
    const int xcd = blockIdx.x & 7;
    const int i   = blockIdx.x >> 3;            // [0, 17*NCT)
    int rloc, ct;
    if (i < 12 * NCT) {
        const int g = i / (4 * NCT), r = i % (4 * NCT);
        rloc = g * 4 + (r & 3);
        ct   = r >> 2;
    } else {
        const int j = i - 12 * NCT;
        rloc = 12 + j % 5;
        ct   = j / 5;
    }
    const int rt = xcd * 17 + rloc;

    const int row0 = rt * 128;
    if (row0 >= s_off[NEXP]) return;
    int e = 0;
    #pragma unroll
    for (int ii = 0; ii < NEXP - 1; ++ii) if (row0 >= s_off[ii + 1]) e = ii + 1;

    const int wv = threadIdx.x >> 6, ln = threadIdx.x & 63;

    // staging sources (pre-swizzled chunk; c is ii-independent: (8*ii)&7==0)
    const int rbase = 32 * wv + (ln >> 3);        // tile row for ii=0
    const int c     = (ln & 7) ^ (ln >> 3);       // swizzled 16B chunk
    const f16* srcA[4];
    if (G1) {
        #pragma unroll
        for (int ii = 0; ii < 4; ++ii)
            srcA[ii] = A + (long)tok_list[row0 + rbase + 8 * ii] * DMODEL + c * 8;
    } else {
        srcA[0] = A + (long)(row0 + rbase) * HDIM + c * 8;
    }
    const f16* srcB = Wt + ((long)e * NJ + ct * 128 + rbase) * K + c * 8;

    f32x4 acc[4][4] = {};
    const int wr = wv >> 1, wc = wv & 1;
    const int l16 = ln & 15, lk = ln >> 4;

    for (int k0 = 0; k0 < K; k0 += 64) {
        #pragma unroll
        for (int ii = 0; ii < 4; ++ii) {
            const f16* sa = G1 ? (srcA[ii] + k0) : (srcA[0] + (size_t)(8 * ii) * K + k0);
            gload16(sa, &lA[(32 * wv + 8 * ii) * 64]);
            gload16(srcB + (size_t)(8 * ii) * K + k0, &lB[(32 * wv + 8 * ii) * 64]);
        }
        __syncthreads();
        #pragma unroll
        for (int kk = 0; kk < 2; ++kk) {
            f16x8 af[4], bf[4];
            #pragma unroll
            for (int m = 0; m < 4; ++m) {
                int r = wr * 64 + m * 16 + l16;
                int ch = (kk * 4 + lk) ^ (r & 7);
                af[m] = *(const f16x8*)&lA[r * 64 + ch * 8];
            }
            #pragma unroll
            for (int n = 0; n < 4; ++n) {
                int j = wc * 64 + n * 16 + l16;
                int ch = (kk * 4 + lk) ^ (j & 7);
                bf[n] = *(const f16x8*)&lB[j * 64 + ch * 8];
            }
            #pragma unroll
            for (int m = 0; m < 4; ++m)
                #pragma unroll
                for (int n = 0; n < 4; ++n)
                    acc[m][n] = __builtin_amdgcn_mfma_f32_16x16x32_f16(af[m], bf[n], acc[m][n], 0, 0, 0);
        }
        __syncthreads();
    }

    if (G1) {
        #pragma unroll
        for (int m = 0; m < 4; ++m) {
            int rb = row0 + wr * 64 + m * 16 + lk * 4;
            #pragma unroll
            for (int n = 0; n < 4; ++n) {
                int cc = ct * 128 + wc * 64 + n * 16 + l16;
                #pragma unroll
                for (int j2 = 0; j2 < 4; ++j2) {
                    float v = acc[m][n][j2];
                    v = v / (1.f + __expf(-v));           // silu
                    Hout[(long)(rb + j2) * HDIM + cc] = (f16)v;
                }
            }
        }
    } else {
        #pragma unroll
        for (int m = 0; m < 4; ++m) {
            int rb = row0 + wr * 64 + m * 16 + lk * 4;
            #pragma unroll
            for (int j2 = 0; j2 < 4; ++j2) {
                int p = pair_list[rb + j2];
                if (p >= 0) {
                    f16* yp = Yp + (long)p * DMODEL + ct * 128 + wc * 64 + l16;
                    #pragma unroll
                    for (int n = 0; n < 4; ++n)
                        yp[n * 16] = (f16)acc[m][n][j2];
                }
            }
        }
    }
}

// ---------------- combine: out[n] = w0*Yp[2n] + w1*Yp[2n+1] ----------------
__global__ __launch_bounds__(256) void combine_k(
    const f16* __restrict__ Yp, const float* __restrict__ ch_w,
    float* __restrict__ out)
{
    const int n = blockIdx.x, t = threadIdx.x;
    const float w0 = ch_w[n * 2], w1 = ch_w[n * 2 + 1];
    const f16x8 a = *(const f16x8*)(Yp + ((long)n * 2) * DMODEL + t * 8);
    const f16x8 b = *(const f16x8*)(Yp + ((long)n * 2 + 1) * DMODEL + t * 8);
    float4 o0, o1;
    o0.x = w0 * (float)a[0] + w1 * (float)b[0];
    o0.y = w0 * (float)a[1] + w1 * (float)b[1];
    o0.z = w0 * (float)a[2] + w1 * (float)b[2];
    o0.w = w0 * (float)a[3] + w1 * (float)b[3];
    o1.x = w0 * (float)a[4] + w1 * (float)b[4];
    o1.y = w0 * (float)a[5] + w1 * (float)b[5];
    o1.z = w0 * (float)a[6] + w1 * (float)b[6];
    o1.w = w0 * (float)a[7] + w1 * (float)b[7];
    float* op = out + (long)n * DMODEL + t * 8;
    *(float4*)op = o0;
    *(float4*)(op + 4) = o1;
}

// ---------------- launch ---------------------------------------------------
extern "C" void kernel_launch(void* const* d_in, const int* in_sizes, int n_in,
                              void* d_out, int out_size, void* d_ws, size_t ws_size,
                              hipStream_t stream)
{
    const float* x  = (const float*)d_in[0];
    const float* Wg = (const float*)d_in[1];
    const float* W1 = (const float*)d_in[2];
    const float* W2 = (const float*)d_in[3];
    float* out = (float*)d_out;

    char* ws = (char*)d_ws;
    size_t o = 0;
    auto alloc = [&](size_t bytes) { size_t r = o; o = (o + bytes + 255) & ~(size_t)255; return r; };
    int*   poff      = (int*)(ws + alloc((NEXP + 1) * 4));
    float* gates     = (float*)(ws + alloc((size_t)N_TOK * NEXP * 4));
    int*   ch_e      = (int*)(ws + alloc((size_t)N_TOK * 2 * 4));
    float* ch_w      = (float*)(ws + alloc((size_t)N_TOK * 2 * 4));
    int*   tok_list  = (int*)(ws + alloc((size_t)MAX_ROWS * 4));
    int*   pair_list = (int*)(ws + alloc((size_t)MAX_ROWS * 4));
    f16*   x16       = (f16*)(ws + alloc((size_t)N_TOK * DMODEL * 2));          // 32 MiB
    f16*   W1t       = (f16*)(ws + alloc((size_t)NEXP * DMODEL * HDIM * 2));    // 32 MiB, contiguous after x16
    f16*   W2t       = (f16*)(ws + alloc((size_t)NEXP * DMODEL * HDIM * 2));
    f16*   hbuf      = (f16*)(ws + alloc((size_t)MAX_ROWS * HDIM * 2));
    // Yp (N_TOK*2 x DMODEL fp16 = 64 MiB) aliases [x16][W1t] — both dead before G2 writes it.
    f16*   Yp        = x16;
    (void)ws_size; (void)in_sizes; (void)n_in;

    hipMemsetAsync(tok_list, 0, (size_t)MAX_ROWS * 4, stream);
    hipMemsetAsync(pair_list, 0xFF, (size_t)MAX_ROWS * 4, stream);   // -1 = padding row

    prep_k<<<2560, 1024, 0, stream>>>(x, Wg, W1, W2, x16, W1t, W2t, ch_e, ch_w, gates);
    route_k<<<1, TPB_R, 0, stream>>>(ch_e, gates, poff, tok_list, pair_list,
                                     out + (size_t)N_TOK * DMODEL);
    ggemm_k<true ><<<ROW_TILES * (HDIM / 128), 256, 0, stream>>>(x16, W1t, poff, tok_list, pair_list, hbuf, nullptr);
    ggemm_k<false><<<ROW_TILES * (DMODEL / 128), 256, 0, stream>>>(hbuf, W2t, poff, tok_list, pair_list, nullptr, Yp);
    combine_k<<<N_TOK, 256, 0, stream>>>(Yp, ch_w, out);
}